// Round 6
// baseline (157.046 us; speedup 1.0000x reference)
//
#include <hip/hip_runtime.h>

// SSIM loss v13: 2 output columns per lane on the v12 (=v7+rcp) schedule.
// v12 anchor: 731 cyc/wave-step, VALU 424 (58%), occupancy- and
// inst-count-insensitive. Structural cost: 11 ds_read_b64 per 1 output/lane
// (every value re-read 11x). Adjacent columns share 10/11 taps, so one lane
// computing cols (2L, 2L+1) needs 12 LDS values = 5 ds_read_b128 + 2
// ds_read_b64 for TWO outputs: LDS ops/output 11 -> 3.5, wave-steps
// 227K -> 129K (4 strips x 16 chunks, CH_H=32, 768 blocks = 3/CU exact).
// Ring doubles to 110 floats/lane -> NO launch-bounds min clause (v8 lesson:
// forced cap => scratch spill; unconstrained allocator never spilled).
// Spill tripwire: WRITE_SIZE must stay ~24KB.
// Predicted: VALUBusy 58->65-75%, kernel 67.5 -> ~47-55us, FETCH ~72MB.

#define BATCH  16
#define CHAN   3
#define H_     512
#define W_     512
#define HW     (H_ * W_)
#define CH_H   32
#define NSTEP  (CH_H + 10)          // 42
#define NPIX   ((long)BATCH*CHAN*H_*W_)

// Normalized 11-tap Gaussian, sigma=1.5 (constants gave absmax 0 in v1/v2/v6).
#define GW0 0.0010284f
#define GW1 0.0075988f
#define GW2 0.0360008f
#define GW3 0.1093554f
#define GW4 0.2130056f
#define GW5 0.2660117f

typedef float v2  __attribute__((ext_vector_type(2)));
typedef float v4f __attribute__((ext_vector_type(4)));

__device__ __forceinline__ float wg(int k) {  // k literal -> folds to constant
    return (k == 0 || k == 10) ? GW0
         : (k == 1 || k == 9)  ? GW1
         : (k == 2 || k == 8)  ? GW2
         : (k == 3 || k == 7)  ? GW3
         : (k == 4 || k == 6)  ? GW4 : GW5;
}

__device__ __forceinline__ v2 pfma(v2 a, v2 b, v2 c) {
#if __has_builtin(__builtin_elementwise_fma)
    return __builtin_elementwise_fma(a, b, c);
#else
    v2 r; r.x = fmaf(a.x, b.x, c.x); r.y = fmaf(a.y, b.y, c.y); return r;
#endif
}
__device__ __forceinline__ v2 psfma(float s, v2 b, v2 c) {  // (s,s)*b + c
    v2 sv; sv.x = s; sv.y = s;
    return pfma(sv, b, c);
}

__device__ __forceinline__ float ssim_retire(float mu1, float mu2,
                                             float x11, float x22, float x12) {
    const float c1 = 1.0e-4f;
    const float c2 = 9.0e-4f;
    float mu1s = mu1 * mu1;
    float mu2s = mu2 * mu2;
    float m12  = mu1 * mu2;
    float num  = (2.0f * m12 + c1) * (2.0f * (x12 - m12) + c2);
    float den  = (mu1s + mu2s + c1) * ((x11 - mu1s) + (x22 - mu2s) + c2);
#if __has_builtin(__builtin_amdgcn_rcpf)
    float l = 1.0f - num * __builtin_amdgcn_rcpf(den);   // v_rcp_f32, ~1 ulp
#else
    float l = 1.0f - num / den;
#endif
    return fminf(fmaxf(l, 0.0f), 1.0f);
}

// Slot i state, two columns A/B: P=(mu1,mu2), Q=(x11,x22), E=x12 each.
#define DECL(i) v2 PA##i = {0.f,0.f}, QA##i = {0.f,0.f}, PB##i = {0.f,0.f}, \
                   QB##i = {0.f,0.f}; float EA##i = 0.f, EB##i = 0.f
#define ACCI(i) do { const float wj_ = wg(10 - (i));             \
    PA##i = psfma(wj_, hmmA, PA##i);                             \
    QA##i = psfma(wj_, hssA, QA##i);                             \
    EA##i = fmaf(wj_, hm12A, EA##i);                             \
    PB##i = psfma(wj_, hmmB, PB##i);                             \
    QB##i = psfma(wj_, hssB, QB##i);                             \
    EB##i = fmaf(wj_, hm12B, EB##i); } while (0)
#define SHIFT(i, j) PA##i = PA##j; QA##i = QA##j; EA##i = EA##j; \
                    PB##i = PB##j; QB##i = QB##j; EB##i = EB##j

// One horizontal tap on packed (x1,x2) value ab_ with literal weight k_.
#define HT_A(ab_, k_) { v2 t = (ab_) * wg(k_); hmmA += t; \
    hssA = pfma(t, (ab_), hssA); hm12A = fmaf(t.x, (ab_).y, hm12A); }
#define HT_B(ab_, k_) { v2 t = (ab_) * wg(k_); hmmB += t; \
    hssB = pfma(t, (ab_), hssB); hm12B = fmaf(t.x, (ab_).y, hm12B); }

__global__ __launch_bounds__(256) void ssim_kernel(const float* __restrict__ img1,
                                                   const float* __restrict__ img2,
                                                   float* __restrict__ out) {
    // Per-wave row buffer: 140 interleaved (img1,img2) col-pairs, 144 padded.
    // Local pair p <-> global col (c0 - 6 + p).
    __shared__ __align__(16) v2 sp[4][144];
    __shared__ float wsum[4];

    const int tid  = threadIdx.x;
    const int lane = tid & 63;
    const int wv   = tid >> 6;

    const int wid   = blockIdx.x * 4 + wv;     // 0..3071
    const int plane = wid >> 6;                // 48 planes, 64 waves each
    const int rem   = wid & 63;
    const int strip = rem & 3;                 // 0..3 (128 cols each)
    const int chunk = rem >> 2;                // 0..15 (32 rows each)
    const int y0 = chunk * CH_H;
    const int c0 = strip * 128;

    // Main load: lane L owns global col pair (c0-6+2L, c0-7+2L+1); whole pair
    // is in- or out-of-range together (left edge only, strip 0 lanes 0..2).
    const int  cg   = c0 - 6 + 2 * lane;       // even; max 504 -> in range
    const bool cok  = (cg >= 0);
    const int  cix  = cok ? cg : 0;
    const float msk = cok ? 1.0f : 0.0f;
    // Halo load: lanes 0..5 own col pair (c0+122+2L, +1); right edge only.
    const int  hg   = c0 + 122 + 2 * lane;
    const bool hok  = (lane < 6) && (hg + 1 < W_);
    const int  hix  = hok ? hg : 0;
    const float hmsk = hok ? 1.0f : 0.0f;

    const size_t pb = (size_t)plane * HW;
    const float* __restrict__ p1 = img1 + pb;   // wave-uniform bases
    const float* __restrict__ p2 = img2 + pb;

    v2* st = sp[wv];

    DECL(0); DECL(1); DECL(2); DECL(3); DECL(4); DECL(5);
    DECL(6); DECL(7); DECL(8); DECL(9); DECL(10);
    float lsum = 0.0f;

    // Preload first h-row (r = y0 - 5; zero if OOB -> matches zero padding).
    v2 ma, mb, ha, hb;                          // main/halo, img1/img2
    {
        int r = y0 - 5;
        bool rok = (unsigned)r < (unsigned)H_;
        size_t off = (size_t)(rok ? r : 0) * W_;
        float mm = rok ? msk : 0.0f, hm = rok ? hmsk : 0.0f;
        ma = *(const v2*)(p1 + off + cix) * mm;
        mb = *(const v2*)(p2 + off + cix) * mm;
        ha = *(const v2*)(p1 + off + hix) * hm;
        hb = *(const v2*)(p2 + off + hix) * hm;
    }

#pragma unroll 2
    for (int step = 0; step < NSTEP; ++step) {
        const int yy = step - 10;              // output row retired this step

        // 1. Stage current h-row: main pair as one ds_write_b128, halo ditto.
        {
            v4f w; w.x = ma.x; w.y = mb.x; w.z = ma.y; w.w = mb.y;
            *(v4f*)&st[2 * lane] = w;
            if (lane < 6) {
                v4f wh; wh.x = ha.x; wh.y = hb.x; wh.z = ha.y; wh.w = hb.y;
                *(v4f*)&st[128 + 2 * lane] = wh;
            }
        }
        __asm__ __volatile__("" ::: "memory");   // writes complete before reads

        // 2. Prefetch next h-row (r = y0 + step - 4); independent of step.
        {
            int r = y0 + step - 4;
            bool rok = (unsigned)r < (unsigned)H_;
            size_t off = (size_t)(rok ? r : 0) * W_;
            float mm = rok ? msk : 0.0f, hm = rok ? hmsk : 0.0f;
            ma = *(const v2*)(p1 + off + cix) * mm;
            mb = *(const v2*)(p2 + off + cix) * mm;
            ha = *(const v2*)(p1 + off + hix) * hm;
            hb = *(const v2*)(p2 + off + hix) * hm;
        }

        // 3. Horizontal 11-tap for BOTH columns. Window: local pairs
        //    2L+1 .. 2L+12 (12 values, shared 10/11 between A and B).
        //    m1, m12 via ds_read_b64; m2..m11 via 5x ds_read_b128.
        v2 m1  = st[2 * lane + 1];
        v4f r1 = *(const v4f*)&st[2 * lane + 2];
        v4f r2 = *(const v4f*)&st[2 * lane + 4];
        v4f r3 = *(const v4f*)&st[2 * lane + 6];
        v4f r4 = *(const v4f*)&st[2 * lane + 8];
        v4f r5 = *(const v4f*)&st[2 * lane + 10];
        v2 m12 = st[2 * lane + 12];
        v2 m2  = {r1.x, r1.y}, m3  = {r1.z, r1.w};
        v2 m4  = {r2.x, r2.y}, m5  = {r2.z, r2.w};
        v2 m6  = {r3.x, r3.y}, m7  = {r3.z, r3.w};
        v2 m8  = {r4.x, r4.y}, m9  = {r4.z, r4.w};
        v2 m10 = {r5.x, r5.y}, m11 = {r5.z, r5.w};

        // Column A (global col c0+2L): taps m1..m11, weights wg(0..10).
        v2 hmmA = m1 * wg(0);
        v2 hssA = hmmA * m1;
        float hm12A = hmmA.x * m1.y;
        HT_A(m2, 1); HT_A(m3, 2); HT_A(m4, 3); HT_A(m5, 4); HT_A(m6, 5);
        HT_A(m7, 6); HT_A(m8, 7); HT_A(m9, 8); HT_A(m10, 9); HT_A(m11, 10);
        // Column B (global col c0+2L+1): taps m2..m12, weights wg(0..10).
        v2 hmmB = m2 * wg(0);
        v2 hssB = hmmB * m2;
        float hm12B = hmmB.x * m2.y;
        HT_B(m3, 1); HT_B(m4, 2); HT_B(m5, 3); HT_B(m6, 4); HT_B(m7, 5);
        HT_B(m8, 6); HT_B(m9, 7); HT_B(m10, 8); HT_B(m11, 9); HT_B(m12, 10);
        __asm__ __volatile__("" ::: "memory");   // next writes stay after reads

        // 4. Accumulate into the 11 in-flight output rows (both columns).
        ACCI(0); ACCI(1); ACCI(2); ACCI(3); ACCI(4); ACCI(5);
        ACCI(6); ACCI(7); ACCI(8); ACCI(9); ACCI(10);

        // 5. Retire output row yy (slot 0 complete, both columns).
        if (yy >= 0) {
            lsum += ssim_retire(PA0.x, PA0.y, QA0.x, QA0.y, EA0);
            lsum += ssim_retire(PB0.x, PB0.y, QB0.x, QB0.y, EB0);
        }

        // 6. Shift the register ring (pure SSA renames; unroll-2 elides half).
        SHIFT(0, 1); SHIFT(1, 2); SHIFT(2, 3); SHIFT(3, 4); SHIFT(4, 5);
        SHIFT(5, 6); SHIFT(6, 7); SHIFT(7, 8); SHIFT(8, 9); SHIFT(9, 10);
        PA10 = (v2){0.f, 0.f}; QA10 = (v2){0.f, 0.f}; EA10 = 0.f;
        PB10 = (v2){0.f, 0.f}; QB10 = (v2){0.f, 0.f}; EB10 = 0.f;
    }

    // Reduction: wave shuffle -> LDS -> one atomic per block.
#pragma unroll
    for (int off = 32; off > 0; off >>= 1) lsum += __shfl_down(lsum, off);
    if (lane == 0) wsum[wv] = lsum;
    __syncthreads();
    if (tid == 0) {
        float bs = wsum[0] + wsum[1] + wsum[2] + wsum[3];
        atomicAdd(out, bs * (0.5f / (float)NPIX));
    }
}

extern "C" void kernel_launch(void* const* d_in, const int* in_sizes, int n_in,
                              void* d_out, int out_size, void* d_ws, size_t ws_size,
                              hipStream_t stream) {
    const float* img1 = (const float*)d_in[0];
    const float* img2 = (const float*)d_in[1];
    float* out = (float*)d_out;

    hipMemsetAsync(out, 0, sizeof(float), stream);

    // 4 strips x 16 chunks x 48 planes = 3072 waves = 768 blocks = 3/CU.
    ssim_kernel<<<dim3(4 * 16 * BATCH * CHAN / 4), 256, 0, stream>>>(img1, img2, out);
}